// Round 8
// baseline (241.156 us; speedup 1.0000x reference)
//
#include <hip/hip_runtime.h>
#include <hip/hip_bf16.h>

typedef __hip_bfloat16 bf16;
typedef __attribute__((ext_vector_type(8))) short short8;
typedef __attribute__((ext_vector_type(4))) float f32x4;

#define MFMA16(A, B, C) __builtin_amdgcn_mfma_f32_16x16x32_bf16((A), (B), (C), 0, 0, 0)

__device__ __forceinline__ unsigned pkbf(float a, float b) {
    __hip_bfloat162 h2 = __float22bfloat162_rn(make_float2(a, b));
    return *reinterpret_cast<unsigned*>(&h2);
}

// ---------------- prep: W fp32 -> frag-major bf16 in ws (verified) ----------------
__global__ __launch_bounds__(256) void prep_w(const float* __restrict__ wq,
                                              const float* __restrict__ wk,
                                              const float* __restrict__ wv,
                                              bf16* __restrict__ wsW)
{
    const int t = (int)blockIdx.x * 256 + (int)threadIdx.x;   // 0..24575
    const int lane = t & 63, kk = (t >> 6) & 7, mt = (t >> 9) & 15, proj = t >> 13;
    const float* W = (proj == 0) ? wq : ((proj == 1) ? wk : wv);
    const int row = mt * 16 + (lane & 15);
    const int col = kk * 32 + (lane >> 4) * 8;
    bf16* dst = wsW + (size_t)t * 8;
#pragma unroll
    for (int j = 0; j < 8; ++j) dst[j] = __float2bfloat16(W[row * 256 + col + j]);
}

// LDS byte map:
//   X  [64 row=col][256 c] bf16 @0, stride 512, swz ^((row&7)<<4)   32768 ; VL aliases after V-proj
//   VL [8px][256a][8t] bf16 @0, swz ^(((px^(a>>3))&7)<<4)          32768
//   QL half [4px][8s][264a] @32768, stride 528, swz ^((px&7)<<4)    16896
//   KL half [4px][8t][264a] @49664                                  16896
//   PL [8px][9][8] bf16 @66560                                       1152   -> total 67712
#define VLB 0
#define QLB 32768
#define KLB 49664
#define PLB 66560

__global__ __launch_bounds__(512, 4)
void fused_sa(const float* __restrict__ x,
              const float* __restrict__ bq, const float* __restrict__ bk,
              const float* __restrict__ bv,
              const bf16* __restrict__ wsW,
              float* __restrict__ out)
{
    __shared__ __align__(16) char SM[67712];

    const int tid = (int)threadIdx.x;
    const int l = tid & 63, w = tid >> 6, h = l >> 4, c15 = l & 15;
    const int p = c15 & 7, beta = c15 >> 3;

    const int wg = ((int)blockIdx.x & 7) * 256 + ((int)blockIdx.x >> 3);
    const int b = wg >> 9, p0 = (wg & 511) * 8;

    const short8* wsv = (const short8*)wsW;

    // ---- monolithic X stage (one drain) ----
    {
        const int p2 = (l & 3) * 2, chi = l >> 2;
        const size_t xbase = ((size_t)((b * 8 + w) * 256)) * 4096 + p0 + p2;
        float2 xr[16];
#pragma unroll
        for (int i = 0; i < 16; ++i)
            xr[i] = *(const float2*)&x[xbase + (size_t)(i * 16 + chi) * 4096];
        const int r0 = w * 8 + p2, r1 = r0 + 1;
#pragma unroll
        for (int i = 0; i < 16; ++i) {
            const int c = i * 16 + chi;
            *(bf16*)(SM + ((r0 * 512 + c * 2) ^ ((r0 & 7) << 4))) = __float2bfloat16(xr[i].x);
            *(bf16*)(SM + ((r1 * 512 + c * 2) ^ ((r1 & 7) << 4))) = __float2bfloat16(xr[i].y);
        }
    }
    __syncthreads();   // B1: X ready

    // ---- QK projection (single 8-kg loop from LDS) ----
    f32x4 aQ0[4] = {}, aQ1[4] = {}, aK0[4] = {}, aK1[4] = {};
#pragma unroll
    for (int kg = 0; kg < 8; ++kg) {
        const short8 fQ0 = wsv[((0 * 16 + 2 * w)     * 8 + kg) * 64 + l];
        const short8 fQ1 = wsv[((0 * 16 + 2 * w + 1) * 8 + kg) * 64 + l];
        const short8 fK0 = wsv[((1 * 16 + 2 * w)     * 8 + kg) * 64 + l];
        const short8 fK1 = wsv[((1 * 16 + 2 * w + 1) * 8 + kg) * 64 + l];
#pragma unroll
        for (int nt = 0; nt < 4; ++nt) {
            const int row = nt * 16 + c15;
            const short8 bx = *(const short8*)(SM +
                ((row * 512 + (kg * 32 + h * 8) * 2) ^ ((row & 7) << 4)));
            aQ0[nt] = MFMA16(fQ0, bx, aQ0[nt]);
            aQ1[nt] = MFMA16(fQ1, bx, aQ1[nt]);
            aK0[nt] = MFMA16(fK0, bx, aK0[nt]);
            aK1[nt] = MFMA16(fK1, bx, aK1[nt]);
        }
    }

    // biases (resident)
    const float4 bq0 = *(const float4*)&bq[(2 * w) * 16 + 4 * h];
    const float4 bq1 = *(const float4*)&bq[(2 * w + 1) * 16 + 4 * h];
    const float4 bk0 = *(const float4*)&bk[(2 * w) * 16 + 4 * h];
    const float4 bk1 = *(const float4*)&bk[(2 * w + 1) * 16 + 4 * h];
    const float bq0v[4] = {bq0.x, bq0.y, bq0.z, bq0.w}, bq1v[4] = {bq1.x, bq1.y, bq1.z, bq1.w};
    const float bk0v[4] = {bk0.x, bk0.y, bk0.z, bk0.w}, bk1v[4] = {bk1.x, bk1.y, bk1.z, bk1.w};

    // ---- two px-halves: {Q/K epi half, barrier, scores half} ----
#pragma unroll
    for (int half = 0; half < 2; ++half) {
        // Q epilogue (R6/R7-verified shuffle-pack), gated to this px-half
#pragma unroll
        for (int r = 0; r < 4; ++r) {
            unsigned wds[4];
#pragma unroll
            for (int nt = 0; nt < 4; ++nt) {
                const float a0 = aQ0[nt][r] + bq0v[r];
                const float a1 = aQ1[nt][r] + bq1v[r];
                const float send = beta ? a0 : a1;
                const float recv = __shfl_xor(send, 8);
                const float own  = beta ? a1 : a0;
                wds[nt] = beta ? pkbf(recv, own) : pkbf(own, recv);
            }
            if ((p >> 2) == half) {
                const int G = 16 * beta + 4 * h + r;
                *(uint4*)(SM + QLB + (((p & 3) * 4224 + w * 528 + G * 16) ^ ((p & 7) << 4))) =
                    make_uint4(wds[0], wds[1], wds[2], wds[3]);
            }
        }
        // K epilogue (verified), gated
        {
            const bool lower = (h < 2);
#pragma unroll
            for (int r = 0; r < 4; ++r) {
                const int t = 4 * (h & 1) + r;
#pragma unroll
                for (int nt = 0; nt < 4; ++nt) {
                    const float a0 = aK0[nt][r] + bk0v[r];
                    const float a1 = aK1[nt][r] + bk1v[r];
                    const float r0 = __shfl_xor(a0, 32);
                    const float r1 = __shfl_xor(a1, 32);
                    const float j0 = lower ? a0 : r0;
                    const float j1 = lower ? r0 : a0;
                    const float j2 = lower ? a1 : r1;
                    const float j3 = lower ? r1 : a1;
                    if (((nt & 1) == (h >> 1)) && ((p >> 2) == half)) {
                        const int a = ((2 * nt + beta) * 4 + (w >> 1)) * 8 + (w & 1) * 4;
                        *(uint2*)(SM + KLB + (((p & 3) * 4224 + t * 528 + a * 2) ^ ((p & 7) << 4))) =
                            make_uint2(pkbf(j0, j1), pkbf(j2, j3));
                    }
                }
            }
        }
        __syncthreads();   // B2/B4: QL/KL half ready

        // scores + softmax for this half (waves 2*half .. 2*half+1; R7-verified)
        if ((w >> 1) == half) {
            const int pxr = c15 >> 3, st = c15 & 7;
            const int px = 2 * w + pxr;
            f32x4 sacc = {0.f, 0.f, 0.f, 0.f};
#pragma unroll
            for (int kk = 0; kk < 8; ++kk) {
                const int off = ((px & 3) * 4224 + st * 528 + (kk * 32 + h * 8) * 2) ^ ((px & 7) << 4);
                const short8 qa = *(const short8*)(SM + QLB + off);
                const short8 kb = *(const short8*)(SM + KLB + off);
                sacc = MFMA16(qa, kb, sacc);
            }
            const bool valid = ((h >> 1) == pxr);
            const int pxo = 2 * w + (h >> 1);
            bf16 (*PL)[9][8] = (bf16 (*)[9][8])(SM + PLB);
#pragma unroll
            for (int r = 0; r < 4; ++r) {
                const float S = sacc[r] * 0.0625f;
                float m = S;
                m = fmaxf(m, __shfl_xor(m, 1));
                m = fmaxf(m, __shfl_xor(m, 2));
                m = fmaxf(m, __shfl_xor(m, 4));
                const float e = __expf(S - m);
                float sm = e;
                sm += __shfl_xor(sm, 1);
                sm += __shfl_xor(sm, 2);
                sm += __shfl_xor(sm, 4);
                if (valid) PL[pxo][4 * (h & 1) + r][st] = __float2bfloat16(e / sm);
            }
        }
        if (half == 0) __syncthreads();   // B3: scores-h1 done reading QL/KL
    }

    // ---- V projection (all waves; overlaps scores-h2's tail via B5 below) ----
    const int Mv = ((w >> 1) << 2) | (w & 1);
    f32x4 aV0[4] = {}, aV1[4] = {};
#pragma unroll
    for (int kg = 0; kg < 8; ++kg) {
        const short8 fV0 = wsv[((2 * 16 + Mv)     * 8 + kg) * 64 + l];
        const short8 fV1 = wsv[((2 * 16 + Mv + 2) * 8 + kg) * 64 + l];
#pragma unroll
        for (int nt = 0; nt < 4; ++nt) {
            const int row = nt * 16 + c15;
            const short8 bx = *(const short8*)(SM +
                ((row * 512 + (kg * 32 + h * 8) * 2) ^ ((row & 7) << 4)));
            aV0[nt] = MFMA16(fV0, bx, aV0[nt]);
            aV1[nt] = MFMA16(fV1, bx, aV1[nt]);
        }
    }
    __syncthreads();   // B5: all X reads done; scores-h2 done; X region free

    // ---- V epilogue -> VL (verified zero-shuffle map) ----
    {
        const float4 b0 = *(const float4*)&bv[Mv * 16 + 4 * h];
        const float4 b1 = *(const float4*)&bv[(Mv + 2) * 16 + 4 * h];
        const float b0v[4] = {b0.x, b0.y, b0.z, b0.w}, b1v[4] = {b1.x, b1.y, b1.z, b1.w};
        const int tp2 = 2 * (w >> 1);
#pragma unroll
        for (int r = 0; r < 4; ++r)
#pragma unroll
            for (int nt = 0; nt < 4; ++nt) {
                const unsigned wd = pkbf(aV0[nt][r] + b0v[r], aV1[nt][r] + b1v[r]);
                const int aV = (16 * (w & 1) + 4 * h + r) * 8 + 2 * nt + beta;
                *(unsigned*)(SM + VLB +
                    ((p * 4096 + aV * 16 + tp2 * 2) ^ (((p ^ (aV >> 3)) & 7) << 4))) = wd;
            }
    }
    __syncthreads();   // B6: VL + PL ready

    // ---- PV -> coalesced float4 stores (verified; after last barrier) ----
    {
        bf16 (*PL)[9][8] = (bf16 (*)[9][8])(SM + PLB);
        const int pxl = c15 & 3, sl = c15 >> 2;
        const short8 zv = {0, 0, 0, 0, 0, 0, 0, 0};
#pragma unroll
        for (int sg = 0; sg < 2; ++sg) {
            short8 pa[2];
#pragma unroll
            for (int q = 0; q < 2; ++q) {
                const short8 t8 = *(const short8*)&PL[q * 4 + pxl][sg * 4 + sl][0];
                pa[q] = (h == pxl) ? t8 : zv;
            }
            const int s = sg * 4 + h;
#pragma unroll
            for (int ci = 0; ci < 2; ++ci) {
                const int a = (2 * w + ci) * 16 + c15;
                const int s2 = a & 7, a2 = (s << 5) | (a >> 3);
#pragma unroll
                for (int q = 0; q < 2; ++q) {
                    const int px = q * 4 + h;
                    const short8 vb = *(const short8*)(SM + VLB +
                        ((px * 4096 + a * 16) ^ (((px ^ (a >> 3)) & 7) << 4)));
                    f32x4 pacc = {0.f, 0.f, 0.f, 0.f};
                    pacc = MFMA16(pa[q], vb, pacc);
                    *(f32x4*)&out[((size_t)((b * 8 + s2) * 256 + a2)) * 4096 + p0 + q * 4] = pacc;
                }
            }
        }
    }
}

extern "C" void kernel_launch(void* const* d_in, const int* in_sizes, int n_in,
                              void* d_out, int out_size, void* d_ws, size_t ws_size,
                              hipStream_t stream) {
    (void)in_sizes; (void)n_in; (void)out_size; (void)ws_size;
    const float* x  = (const float*)d_in[0];
    const float* wq = (const float*)d_in[1];
    const float* bq = (const float*)d_in[2];
    const float* wk = (const float*)d_in[3];
    const float* bk = (const float*)d_in[4];
    const float* wv = (const float*)d_in[5];
    const float* bv = (const float*)d_in[6];
    float* out = (float*)d_out;
    bf16* wsW  = (bf16*)d_ws;   // 393,216 bytes

    hipLaunchKernelGGL(prep_w, dim3(96), dim3(256), 0, stream, wq, wk, wv, wsW);
    hipLaunchKernelGGL(fused_sa, dim3(2048), dim3(512), 0, stream,
                       x, bq, bk, bv, wsW, out);
}

// Round 9
// 171.776 us; speedup vs baseline: 1.4039x; 1.4039x over previous
//
#include <hip/hip_runtime.h>
#include <hip/hip_bf16.h>

typedef __hip_bfloat16 bf16;
typedef __attribute__((ext_vector_type(8))) short short8;
typedef __attribute__((ext_vector_type(4))) float f32x4;

#define MFMA16(A, B, C) __builtin_amdgcn_mfma_f32_16x16x32_bf16((A), (B), (C), 0, 0, 0)

// Raw workgroup barrier with LDS-only drain: does NOT wait vmcnt, so global
// prefetch loads stay in flight across the barrier (all cross-thread deps in
// this kernel are via LDS; global loads are consumed by their issuing thread,
// compiler inserts per-use vmcnt waits).
__device__ __forceinline__ void bar_lds() {
    asm volatile("s_waitcnt lgkmcnt(0)\n\ts_barrier" ::: "memory");
}

__device__ __forceinline__ unsigned pkbf(float a, float b) {
    __hip_bfloat162 h2 = __float22bfloat162_rn(make_float2(a, b));
    return *reinterpret_cast<unsigned*>(&h2);
}

// ---------------- prep: W fp32 -> frag-major bf16 in ws (verified) ----------------
__global__ __launch_bounds__(256) void prep_w(const float* __restrict__ wq,
                                              const float* __restrict__ wk,
                                              const float* __restrict__ wv,
                                              bf16* __restrict__ wsW)
{
    const int t = (int)blockIdx.x * 256 + (int)threadIdx.x;   // 0..24575
    const int lane = t & 63, kk = (t >> 6) & 7, mt = (t >> 9) & 15, proj = t >> 13;
    const float* W = (proj == 0) ? wq : ((proj == 1) ? wk : wv);
    const int row = mt * 16 + (lane & 15);
    const int col = kk * 32 + (lane >> 4) * 8;
    bf16* dst = wsW + (size_t)t * 8;
#pragma unroll
    for (int j = 0; j < 8; ++j) dst[j] = __float2bfloat16(W[row * 256 + col + j]);
}

// LDS byte map (identical to R7 / 184us-verified):
//   XC [64 col][64 c] bf16 @0      (8192)   swz ^((row&7)<<4)
//   QL [8px][8s][264a] bf16 @8192  (33792)  swz ^((px&7)<<4)      ; VL aliases
//   KL [8px][8t][264a] bf16 @41984 (33792)  swz ^((px&7)<<4)
//   PL [8px][9][8] bf16 @75776     (1152)
//   VL [8px][256a][8t] bf16 @8192  (32768)  swz ^(((px^(a>>3))&7)<<4)
#define QLB 8192
#define KLB 41984
#define VLB 8192
#define PLB 75776

__global__ __launch_bounds__(512, 4)
void fused_sa(const float* __restrict__ x,
              const float* __restrict__ bq, const float* __restrict__ bk,
              const float* __restrict__ bv,
              const bf16* __restrict__ wsW,
              float* __restrict__ out)
{
    __shared__ __align__(16) char SM[76928];

    const int tid = (int)threadIdx.x;
    const int l = tid & 63, w = tid >> 6, h = l >> 4, c15 = l & 15;
    const int p = c15 & 7, beta = c15 >> 3;

    const int wg = ((int)blockIdx.x & 7) * 256 + ((int)blockIdx.x >> 3);
    const int b = wg >> 9, p0 = (wg & 511) * 8;

    const short8* wsv = (const short8*)wsW;
    const int p2 = (l & 3) * 2, chi = l >> 2;    // wave w stages s'=w
    const size_t xbase = ((size_t)((b * 8 + w) * 256)) * 4096 + p0 + p2;

    // =============== PASS 1: Q,K projections over 4 K-chunks ===============
    f32x4 aQ0[4] = {}, aQ1[4] = {}, aK0[4] = {}, aK1[4] = {};
    {
        float2 xr[4];
#pragma unroll
        for (int i = 0; i < 4; ++i)
            xr[i] = *(const float2*)&x[xbase + (size_t)(i * 16 + chi) * 4096];

        for (int cc = 0; cc < 4; ++cc) {
            if (cc) bar_lds();
#pragma unroll
            for (int i = 0; i < 4; ++i) {
                const int c = i * 16 + chi;
                const int r0 = w * 8 + p2, r1 = r0 + 1;
                *(bf16*)(SM + ((r0 * 128 + c * 2) ^ ((r0 & 7) << 4))) = __float2bfloat16(xr[i].x);
                *(bf16*)(SM + ((r1 * 128 + c * 2) ^ ((r1 & 7) << 4))) = __float2bfloat16(xr[i].y);
            }
            if (cc < 3) {
#pragma unroll
                for (int i = 0; i < 4; ++i)
                    xr[i] = *(const float2*)&x[xbase + (size_t)((cc + 1) * 64 + i * 16 + chi) * 4096];
            }
            bar_lds();
#pragma unroll
            for (int k2 = 0; k2 < 2; ++k2) {
                const int kg = cc * 2 + k2;
                const short8 fQ0 = wsv[((0 * 16 + 2 * w)     * 8 + kg) * 64 + l];
                const short8 fQ1 = wsv[((0 * 16 + 2 * w + 1) * 8 + kg) * 64 + l];
                const short8 fK0 = wsv[((1 * 16 + 2 * w)     * 8 + kg) * 64 + l];
                const short8 fK1 = wsv[((1 * 16 + 2 * w + 1) * 8 + kg) * 64 + l];
#pragma unroll
                for (int nt = 0; nt < 4; ++nt) {
                    const int row = nt * 16 + c15;
                    const short8 bx = *(const short8*)(SM +
                        ((row * 128 + (k2 * 32 + h * 8) * 2) ^ ((row & 7) << 4)));
                    aQ0[nt] = MFMA16(fQ0, bx, aQ0[nt]);
                    aQ1[nt] = MFMA16(fQ1, bx, aQ1[nt]);
                    aK0[nt] = MFMA16(fK0, bx, aK0[nt]);
                    aK1[nt] = MFMA16(fK1, bx, aK1[nt]);
                }
            }
        }
    }

    // ---- Q epilogue -> QL (verified shuffle-pack) ----
    {
        const float4 b0 = *(const float4*)&bq[(2 * w) * 16 + 4 * h];
        const float4 b1 = *(const float4*)&bq[(2 * w + 1) * 16 + 4 * h];
        const float b0v[4] = {b0.x, b0.y, b0.z, b0.w}, b1v[4] = {b1.x, b1.y, b1.z, b1.w};
#pragma unroll
        for (int r = 0; r < 4; ++r) {
            unsigned wds[4];
#pragma unroll
            for (int nt = 0; nt < 4; ++nt) {
                const float a0 = aQ0[nt][r] + b0v[r];
                const float a1 = aQ1[nt][r] + b1v[r];
                const float send = beta ? a0 : a1;
                const float recv = __shfl_xor(send, 8);
                const float own  = beta ? a1 : a0;
                wds[nt] = beta ? pkbf(recv, own) : pkbf(own, recv);
            }
            const int G = 16 * beta + 4 * h + r;
            *(uint4*)(SM + QLB + ((p * 4224 + w * 528 + G * 16) ^ ((p & 7) << 4))) =
                make_uint4(wds[0], wds[1], wds[2], wds[3]);
        }
    }
    // ---- K epilogue -> KL (verified) ----
    {
        const float4 b0 = *(const float4*)&bk[(2 * w) * 16 + 4 * h];
        const float4 b1 = *(const float4*)&bk[(2 * w + 1) * 16 + 4 * h];
        const float b0v[4] = {b0.x, b0.y, b0.z, b0.w}, b1v[4] = {b1.x, b1.y, b1.z, b1.w};
        const bool lower = (h < 2);
#pragma unroll
        for (int r = 0; r < 4; ++r) {
            const int t = 4 * (h & 1) + r;
#pragma unroll
            for (int nt = 0; nt < 4; ++nt) {
                const float a0 = aK0[nt][r] + b0v[r];
                const float a1 = aK1[nt][r] + b1v[r];
                const float r0 = __shfl_xor(a0, 32);
                const float r1 = __shfl_xor(a1, 32);
                const float j0 = lower ? a0 : r0;
                const float j1 = lower ? r0 : a0;
                const float j2 = lower ? a1 : r1;
                const float j3 = lower ? r1 : a1;
                if ((nt & 1) == (h >> 1)) {
                    const int a = ((2 * nt + beta) * 4 + (w >> 1)) * 8 + (w & 1) * 4;
                    *(uint2*)(SM + KLB + ((p * 4224 + t * 528 + a * 2) ^ ((p & 7) << 4))) =
                        make_uint2(pkbf(j0, j1), pkbf(j2, j3));
                }
            }
        }
    }
    bar_lds();   // QL/KL ready

    // ---- scores + softmax (waves 0-3; verified) ----
    if (w < 4) {
        const int q = w, pxr = c15 >> 3, st = c15 & 7;
        const int px = 2 * q + pxr;
        f32x4 sacc = {0.f, 0.f, 0.f, 0.f};
#pragma unroll
        for (int kk = 0; kk < 8; ++kk) {
            const int off = (px * 4224 + st * 528 + (kk * 32 + h * 8) * 2) ^ ((px & 7) << 4);
            const short8 qa = *(const short8*)(SM + QLB + off);
            const short8 kb = *(const short8*)(SM + KLB + off);
            sacc = MFMA16(qa, kb, sacc);
        }
        const bool valid = ((h >> 1) == pxr);
        const int pxo = 2 * q + (h >> 1);
        bf16 (*PL)[9][8] = (bf16 (*)[9][8])(SM + PLB);
#pragma unroll
        for (int r = 0; r < 4; ++r) {
            const float S = sacc[r] * 0.0625f;
            float m = S;
            m = fmaxf(m, __shfl_xor(m, 1));
            m = fmaxf(m, __shfl_xor(m, 2));
            m = fmaxf(m, __shfl_xor(m, 4));
            const float e = __expf(S - m);
            float sm = e;
            sm += __shfl_xor(sm, 1);
            sm += __shfl_xor(sm, 2);
            sm += __shfl_xor(sm, 4);
            if (valid) PL[pxo][4 * (h & 1) + r][st] = __float2bfloat16(e / sm);
        }
    }
    bar_lds();   // scores done reading QL; PL ready; VL region free

    // =============== PASS 2: V projection (restage X chunks; L2-hot) ===============
    const int Mv = ((w >> 1) << 2) | (w & 1);
    f32x4 aV0[4] = {}, aV1[4] = {};
    {
        float2 xr[4];
#pragma unroll
        for (int i = 0; i < 4; ++i)
            xr[i] = *(const float2*)&x[xbase + (size_t)(i * 16 + chi) * 4096];

        for (int cc = 0; cc < 4; ++cc) {
            bar_lds();    // prev chunk readers done (and, for cc=0, XC free)
#pragma unroll
            for (int i = 0; i < 4; ++i) {
                const int c = i * 16 + chi;
                const int r0 = w * 8 + p2, r1 = r0 + 1;
                *(bf16*)(SM + ((r0 * 128 + c * 2) ^ ((r0 & 7) << 4))) = __float2bfloat16(xr[i].x);
                *(bf16*)(SM + ((r1 * 128 + c * 2) ^ ((r1 & 7) << 4))) = __float2bfloat16(xr[i].y);
            }
            if (cc < 3) {
#pragma unroll
                for (int i = 0; i < 4; ++i)
                    xr[i] = *(const float2*)&x[xbase + (size_t)((cc + 1) * 64 + i * 16 + chi) * 4096];
            }
            bar_lds();
#pragma unroll
            for (int k2 = 0; k2 < 2; ++k2) {
                const int kg = cc * 2 + k2;
                const short8 fV0 = wsv[((2 * 16 + Mv)     * 8 + kg) * 64 + l];
                const short8 fV1 = wsv[((2 * 16 + Mv + 2) * 8 + kg) * 64 + l];
#pragma unroll
                for (int nt = 0; nt < 4; ++nt) {
                    const int row = nt * 16 + c15;
                    const short8 bx = *(const short8*)(SM +
                        ((row * 128 + (k2 * 32 + h * 8) * 2) ^ ((row & 7) << 4)));
                    aV0[nt] = MFMA16(fV0, bx, aV0[nt]);
                    aV1[nt] = MFMA16(fV1, bx, aV1[nt]);
                }
            }
        }
    }

    // ---- V epilogue -> VL (verified zero-shuffle map) ----
    {
        const float4 b0 = *(const float4*)&bv[Mv * 16 + 4 * h];
        const float4 b1 = *(const float4*)&bv[(Mv + 2) * 16 + 4 * h];
        const float b0v[4] = {b0.x, b0.y, b0.z, b0.w}, b1v[4] = {b1.x, b1.y, b1.z, b1.w};
        const int tp2 = 2 * (w >> 1);
#pragma unroll
        for (int r = 0; r < 4; ++r)
#pragma unroll
            for (int nt = 0; nt < 4; ++nt) {
                const unsigned wd = pkbf(aV0[nt][r] + b0v[r], aV1[nt][r] + b1v[r]);
                const int aV = (16 * (w & 1) + 4 * h + r) * 8 + 2 * nt + beta;
                *(unsigned*)(SM + VLB +
                    ((p * 4096 + aV * 16 + tp2 * 2) ^ (((p ^ (aV >> 3)) & 7) << 4))) = wd;
            }
    }
    bar_lds();   // VL + PL ready

    // ---- PV (verified) -> coalesced float4 stores (after last barrier) ----
    {
        bf16 (*PL)[9][8] = (bf16 (*)[9][8])(SM + PLB);
        const int pxl = c15 & 3, sl = c15 >> 2;
        const short8 zv = {0, 0, 0, 0, 0, 0, 0, 0};
#pragma unroll
        for (int sg = 0; sg < 2; ++sg) {
            short8 pa[2];
#pragma unroll
            for (int q = 0; q < 2; ++q) {
                const short8 t8 = *(const short8*)&PL[q * 4 + pxl][sg * 4 + sl][0];
                pa[q] = (h == pxl) ? t8 : zv;
            }
            const int s = sg * 4 + h;
#pragma unroll
            for (int ci = 0; ci < 2; ++ci) {
                const int a = (2 * w + ci) * 16 + c15;
                const int s2 = a & 7, a2 = (s << 5) | (a >> 3);
#pragma unroll
                for (int q = 0; q < 2; ++q) {
                    const int px = q * 4 + h;
                    const short8 vb = *(const short8*)(SM + VLB +
                        ((px * 4096 + a * 16) ^ (((px ^ (a >> 3)) & 7) << 4)));
                    f32x4 pacc = {0.f, 0.f, 0.f, 0.f};
                    pacc = MFMA16(pa[q], vb, pacc);
                    *(f32x4*)&out[((size_t)((b * 8 + s2) * 256 + a2)) * 4096 + p0 + q * 4] = pacc;
                }
            }
        }
    }
}

extern "C" void kernel_launch(void* const* d_in, const int* in_sizes, int n_in,
                              void* d_out, int out_size, void* d_ws, size_t ws_size,
                              hipStream_t stream) {
    (void)in_sizes; (void)n_in; (void)out_size; (void)ws_size;
    const float* x  = (const float*)d_in[0];
    const float* wq = (const float*)d_in[1];
    const float* bq = (const float*)d_in[2];
    const float* wk = (const float*)d_in[3];
    const float* bk = (const float*)d_in[4];
    const float* wv = (const float*)d_in[5];
    const float* bv = (const float*)d_in[6];
    float* out = (float*)d_out;
    bf16* wsW  = (bf16*)d_ws;   // 393,216 bytes

    hipLaunchKernelGGL(prep_w, dim3(96), dim3(256), 0, stream, wq, wk, wv, wsW);
    hipLaunchKernelGGL(fused_sa, dim3(2048), dim3(512), 0, stream,
                       x, bq, bk, bv, wsW, out);
}